// Round 12
// baseline (781.939 us; speedup 1.0000x reference)
//
#include <hip/hip_runtime.h>
#include <hip/hip_bf16.h>

// GCN: 3 layers, N=50000 nodes, E=600000 edges, feats 128->128->128->64,
// BatchNorm+ReLU between layers. norm = dis[src]*dis[dst] factorized out.
// GEMMs on MFMA bf16 (fp32 accum); intermediate buffers bf16; BN stats fused
// into k_agg (register-accumulated over NPW nodes, one flush per block,
// BN params computed by the LAST agg block - no separate bnparams kernel).
// Agg edge loop is fully masked-8-wide (no serial tail).

#define NCHUNK 1024
#define NSLOT 64
#define NPW 4            // nodes per wave in k_agg

typedef short bf16x8 __attribute__((ext_vector_type(8)));
typedef float f32x4 __attribute__((ext_vector_type(4)));

union FragU { uint4 u; bf16x8 f; };

static __device__ __forceinline__ float4 ld4(const float* p) {
    return *reinterpret_cast<const float4*>(p);
}

// pack two fp32 -> bf16x2 (RNE), memory order lo,hi
static __device__ __forceinline__ unsigned pk2(float lo, float hi) {
    __hip_bfloat162 h = __float22bfloat162_rn(make_float2(lo, hi));
    union { __hip_bfloat162 h2; unsigned u; } c;
    c.h2 = h;
    return c.u;
}
static __device__ __forceinline__ unsigned short bf1(float v) {
    return (unsigned short)(pk2(v, 0.f) & 0xffffu);
}
static __device__ __forceinline__ float bf_lo(unsigned u) { return __uint_as_float(u << 16); }
static __device__ __forceinline__ float bf_hi(unsigned u) { return __uint_as_float(u & 0xffff0000u); }

// Merged: cnt/stats/counter zero-init (blocks < gbInit) + W1/W2/W3 fragment
// prep (blocks >= gbInit; 4 64-lane units per 256-thread block).
// Frag f = t*4+kk; lane l holds B[k = kk*32+(l>>4)*8+j][col = t*16+(l&15)].
__global__ __launch_bounds__(256) void k_setup(int* __restrict__ cnt,
                                               float* __restrict__ stats,
                                               int* __restrict__ counters, int n,
                                               int gbInit,
                                               const float* __restrict__ W1,
                                               const float* __restrict__ W2,
                                               const float* __restrict__ W3,
                                               unsigned short* __restrict__ wf1,
                                               unsigned short* __restrict__ wf2,
                                               unsigned short* __restrict__ wf3) {
    int b = blockIdx.x;
    if (b < gbInit) {
        int i = b * 256 + threadIdx.x;
        if (i < n) cnt[i] = 0;
        if (i < 4 * NSLOT * 128) stats[i] = 0.f;   // ssum1, ssq1, ssum2, ssq2
        if (i < 8) counters[i] = 0;
        return;
    }
    int unit = (b - gbInit) * 4 + (threadIdx.x >> 6);   // 0..79
    if (unit >= 80) return;
    int l = threadIdx.x & 63;
    const float* W; unsigned short* Wf; int NC; int blk;
    if (unit < 32)      { W = W1; Wf = wf1; NC = 128; blk = unit; }
    else if (unit < 64) { W = W2; Wf = wf2; NC = 128; blk = unit - 32; }
    else                { W = W3; Wf = wf3; NC = 64;  blk = unit - 64; }
    int kk = blk & 3;
    int col = (blk >> 2) * 16 + (l & 15);
    int k0 = kk * 32 + (l >> 4) * 8;
    unsigned short* dst = &Wf[((size_t)blk * 64 + l) * 8];
#pragma unroll
    for (int j = 0; j < 8; ++j)
        dst[j] = bf1(W[(size_t)(k0 + j) * NC + col]);
}

__global__ void k_count(const int* __restrict__ dst, int* __restrict__ cnt, int e) {
    int i = blockIdx.x * 256 + threadIdx.x;
    if (i < e) atomicAdd(&cnt[dst[i]], 1);
}

// Stage 1: per-chunk sums of cnt. NCHUNK threads across 4 blocks.
__global__ __launch_bounds__(256) void k_chunksum(const int* __restrict__ cnt,
                                                  int* __restrict__ chunkSum, int n) {
    int t = blockIdx.x * 256 + threadIdx.x;   // 0..NCHUNK-1
    int per = (n + NCHUNK - 1) / NCHUNK;
    int lo = t * per; if (lo > n) lo = n;
    int hi = lo + per; if (hi > n) hi = n;
    int s = 0;
    for (int i = lo; i < hi; ++i) s += cnt[i];
    chunkSum[t] = s;
}

// Stage 2: each of the 4 blocks redundantly scans all NCHUNK chunk sums in
// LDS (4 loads/thread + 256-scan), then writes offs/cursor/dis for its own
// 256 chunks.
__global__ __launch_bounds__(256) void k_chunkwrite(const int* __restrict__ cnt,
                                                    const int* __restrict__ chunkSum,
                                                    int* __restrict__ offs,
                                                    int* __restrict__ cursor,
                                                    float* __restrict__ dis,
                                                    int n, int e) {
    __shared__ int lbase[NCHUNK];
    __shared__ int lth[256];
    int t = threadIdx.x;
    int a0 = chunkSum[t * 4 + 0], a1 = chunkSum[t * 4 + 1];
    int a2 = chunkSum[t * 4 + 2], a3 = chunkSum[t * 4 + 3];
    lth[t] = a0 + a1 + a2 + a3;
    __syncthreads();
    for (int off = 1; off < 256; off <<= 1) {
        int v = (t >= off) ? lth[t - off] : 0;
        __syncthreads();
        lth[t] += v;
        __syncthreads();
    }
    int base = (t == 0) ? 0 : lth[t - 1];
    lbase[t * 4 + 0] = base;
    lbase[t * 4 + 1] = base + a0;
    lbase[t * 4 + 2] = base + a0 + a1;
    lbase[t * 4 + 3] = base + a0 + a1 + a2;
    __syncthreads();
    int cid = blockIdx.x * 256 + t;
    int per = (n + NCHUNK - 1) / NCHUNK;
    int lo = cid * per; if (lo > n) lo = n;
    int hi = lo + per; if (hi > n) hi = n;
    int run = lbase[cid];
    for (int i = lo; i < hi; ++i) {
        offs[i] = run;
        cursor[i] = run;
        int c = cnt[i];
        dis[i] = rsqrtf((float)(c + 1));
        run += c;
    }
    if (cid == 0) offs[n] = e;
}

__global__ void k_scatter(const int* __restrict__ src, const int* __restrict__ dst,
                          int* __restrict__ cursor, int* __restrict__ csr, int e) {
    int i = blockIdx.x * 256 + threadIdx.x;
    if (i < e) {
        int p = atomicAdd(&cursor[dst[i]], 1);
        csr[p] = src[i];
    }
}

// out[row][col] = bf16( dis[row] * sum_k in'(row,k) * W[k][col] )
// in'(row,k) = TRANS ? relu(in*ta[k]+tc[k]) : in.  INBF: input rows are bf16.
//
// MFMA 16x16x32 bf16. Block: 32 rows x NC cols, 256 threads = 4 waves.
// Wave w: rows (w>>1)*16..+16, col-half (w&1)*NC/2. A staged bf16 in LDS
// with XOR swizzle byte^=(row&7)<<4 (G4). B from pre-fragmented Wf.
// Epilogue: acc -> LDS [32][NC+8] (pad -> 2-way banks, free) -> coalesced
// uint4 row stores.
template <bool TRANS, int NC, bool INBF>
__global__ __launch_bounds__(256) void k_gemm(const void* __restrict__ inv,
                                              const uint4* __restrict__ Wf,
                                              const float* __restrict__ dis,
                                              const float* __restrict__ ta,
                                              const float* __restrict__ tc,
                                              unsigned short* __restrict__ out, int n) {
    constexpr int TPW = NC / 32;          // 16-col tiles per wave: 4 or 2
    constexpr int PADC = NC + 8;          // padded u16 row stride (16B-aligned)
    constexpr int SHN = (32 * PADC > 32 * 128) ? 32 * PADC : 32 * 128;
    __shared__ unsigned short sh[SHN];
    const int tid = threadIdx.x;
    const int row0 = blockIdx.x * 32;

    if constexpr (INBF) {
        const unsigned short* in = (const unsigned short*)inv;
#pragma unroll
        for (int it = 0; it < 2; ++it) {
            int flat = it * 256 + tid;
            int r = flat >> 4, j = flat & 15;     // j indexes uint4 (8 bf16)
            int grow = row0 + r;
            uint4 v = make_uint4(0, 0, 0, 0);
            if (grow < n) v = *reinterpret_cast<const uint4*>(&in[(size_t)grow * 128 + j * 8]);
            if (TRANS) {
                int f = j * 8;
                float4 A0 = ld4(&ta[f]), A1 = ld4(&ta[f + 4]);
                float4 C0 = ld4(&tc[f]), C1 = ld4(&tc[f + 4]);
                v.x = pk2(fmaxf(bf_lo(v.x) * A0.x + C0.x, 0.f),
                          fmaxf(bf_hi(v.x) * A0.y + C0.y, 0.f));
                v.y = pk2(fmaxf(bf_lo(v.y) * A0.z + C0.z, 0.f),
                          fmaxf(bf_hi(v.y) * A0.w + C0.w, 0.f));
                v.z = pk2(fmaxf(bf_lo(v.z) * A1.x + C1.x, 0.f),
                          fmaxf(bf_hi(v.z) * A1.y + C1.y, 0.f));
                v.w = pk2(fmaxf(bf_lo(v.w) * A1.z + C1.z, 0.f),
                          fmaxf(bf_hi(v.w) * A1.w + C1.w, 0.f));
            }
            int byte = r * 256 + ((j * 16) ^ ((r & 7) << 4));
            *reinterpret_cast<uint4*>(reinterpret_cast<char*>(sh) + byte) = v;
        }
    } else {
        const float* in = (const float*)inv;
#pragma unroll
        for (int it = 0; it < 4; ++it) {
            int flat = it * 256 + tid;
            int r = flat >> 5, j4 = flat & 31;
            int grow = row0 + r;
            float4 v = make_float4(0.f, 0.f, 0.f, 0.f);
            if (grow < n) v = ld4(&in[(size_t)grow * 128 + j4 * 4]);
            if (TRANS) {
                int f = j4 * 4;
                float4 A = ld4(&ta[f]);
                float4 C = ld4(&tc[f]);
                v.x = fmaxf(v.x * A.x + C.x, 0.f);
                v.y = fmaxf(v.y * A.y + C.y, 0.f);
                v.z = fmaxf(v.z * A.z + C.z, 0.f);
                v.w = fmaxf(v.w * A.w + C.w, 0.f);
            }
            int byte = r * 256 + ((j4 * 8) ^ ((r & 7) << 4));
            *reinterpret_cast<uint2*>(reinterpret_cast<char*>(sh) + byte) =
                make_uint2(pk2(v.x, v.y), pk2(v.z, v.w));
        }
    }
    __syncthreads();

    const int l = tid & 63, w = tid >> 6;
    const int l15 = l & 15, g = l >> 4;
    const int rhalf = (w >> 1) * 16;          // LDS row offset: 0 or 16
    const int tbase = (w & 1) * TPW;          // col-tile offset

    f32x4 acc[TPW];
#pragma unroll
    for (int t = 0; t < TPW; ++t) acc[t] = (f32x4){0.f, 0.f, 0.f, 0.f};

    const int arow = rhalf + l15;
    const char* xb = reinterpret_cast<const char*>(sh) + arow * 256;
    const int aswz = (arow & 7) << 4;

#pragma unroll
    for (int kk = 0; kk < 4; ++kk) {
        FragU a;
        a.u = *reinterpret_cast<const uint4*>(xb + ((kk * 64 + g * 16) ^ aswz));
#pragma unroll
        for (int t = 0; t < TPW; ++t) {
            FragU b;
            b.u = Wf[(size_t)((tbase + t) * 4 + kk) * 64 + l];
            acc[t] = __builtin_amdgcn_mfma_f32_16x16x32_bf16(a.f, b.f, acc[t], 0, 0, 0);
        }
    }

    // epilogue: D[row = g*4+r][col = l15] per tile -> LDS -> coalesced stores
    const int rbase = row0 + rhalf + g * 4;
    float dv[4];
#pragma unroll
    for (int r = 0; r < 4; ++r) {
        int rr = rbase + r;
        dv[r] = (rr < n) ? dis[rr] : 0.f;
    }
    __syncthreads();   // all waves done reading staged A before overwrite
#pragma unroll
    for (int t = 0; t < TPW; ++t) {
        int col = (tbase + t) * 16 + l15;
#pragma unroll
        for (int r = 0; r < 4; ++r) {
            int lrow = rhalf + g * 4 + r;
            sh[lrow * PADC + col] = bf1(acc[t][r] * dv[r]);
        }
    }
    __syncthreads();
    constexpr int U4R = NC / 8;           // uint4 per output row
#pragma unroll
    for (int it = 0; it < (32 * U4R) / 256; ++it) {
        int flat = it * 256 + tid;
        int row = flat / U4R, j = flat % U4R;
        int grow = row0 + row;
        if (grow < n) {
            uint4 v = *reinterpret_cast<const uint4*>(&sh[row * PADC + j * 8]);
            *reinterpret_cast<uint4*>(&out[(size_t)grow * NC + j * 8]) = v;
        }
    }
}

// h[i] = dis[i] * (hs[i] + sum_{src in(i)} hs[src]) + bias.  hs bf16.
// Each wave processes NPW consecutive nodes. Edge loop is masked-8-wide:
// indices clamped to e1-1 (loads always issued, 4 in flight per wave),
// adds predicated -> no serial tail. NC=128: 32 lanes x uint2 per row,
// 2 edges/step via half; writes bf16; BN stats accumulated in registers,
// flushed once per block; the LAST block computes BN params a/cc in-kernel.
// NC=64: one uint per lane; fp32 out, no stats.
template <int NC, bool STATS>
__global__ __launch_bounds__(256) void k_agg(const unsigned short* __restrict__ hs,
                                             const int* __restrict__ offs,
                                             const int* __restrict__ csr,
                                             const float* __restrict__ dis,
                                             const float* __restrict__ bias,
                                             void* __restrict__ outv,
                                             float* __restrict__ ssum,
                                             float* __restrict__ ssq,
                                             const float* __restrict__ gamma,
                                             const float* __restrict__ beta,
                                             float* __restrict__ aOut,
                                             float* __restrict__ ccOut,
                                             int* __restrict__ counter, int n) {
    const int wave = threadIdx.x >> 6, lane = threadIdx.x & 63;
    const int half = lane >> 5, l32 = lane & 31;
    const int nodeBase = blockIdx.x * (4 * NPW) + wave * NPW;

    float4 st = make_float4(0.f, 0.f, 0.f, 0.f);   // stats: sum (half==0)
    float4 sq = make_float4(0.f, 0.f, 0.f, 0.f);   // stats: sumsq

    for (int j = 0; j < NPW; ++j) {
        const int node = nodeBase + j;
        int e0 = 0, e1 = 0;
        if (node < n) { e0 = offs[node]; e1 = offs[node + 1]; }

        if (NC == 128) {
            const uint2* hp = reinterpret_cast<const uint2*>(hs);  // 32 uint2/row
            float4 a0 = make_float4(0.f, 0.f, 0.f, 0.f);
            float4 a1 = a0, a2 = a0, a3 = a0;
            if (half == 0 && node < n) {
                uint2 w = hp[(size_t)node * 32 + l32];             // self-loop
                a0 = make_float4(bf_lo(w.x), bf_hi(w.x), bf_lo(w.y), bf_hi(w.y));
            }
            const int lim = e1 - 1;
            for (int e = e0; e < e1; e += 8) {
                int ee0 = e + 0 + half, ee1 = e + 2 + half;
                int ee2 = e + 4 + half, ee3 = e + 6 + half;
                int i0 = csr[ee0 <= lim ? ee0 : lim];
                int i1 = csr[ee1 <= lim ? ee1 : lim];
                int i2 = csr[ee2 <= lim ? ee2 : lim];
                int i3 = csr[ee3 <= lim ? ee3 : lim];
                uint2 w0 = hp[(size_t)i0 * 32 + l32];
                uint2 w1 = hp[(size_t)i1 * 32 + l32];
                uint2 w2 = hp[(size_t)i2 * 32 + l32];
                uint2 w3 = hp[(size_t)i3 * 32 + l32];
                if (ee0 < e1) { a0.x += bf_lo(w0.x); a0.y += bf_hi(w0.x); a0.z += bf_lo(w0.y); a0.w += bf_hi(w0.y); }
                if (ee1 < e1) { a1.x += bf_lo(w1.x); a1.y += bf_hi(w1.x); a1.z += bf_lo(w1.y); a1.w += bf_hi(w1.y); }
                if (ee2 < e1) { a2.x += bf_lo(w2.x); a2.y += bf_hi(w2.x); a2.z += bf_lo(w2.y); a2.w += bf_hi(w2.y); }
                if (ee3 < e1) { a3.x += bf_lo(w3.x); a3.y += bf_hi(w3.x); a3.z += bf_lo(w3.y); a3.w += bf_hi(w3.y); }
            }
            a0.x += a1.x + a2.x + a3.x;
            a0.y += a1.y + a2.y + a3.y;
            a0.z += a1.z + a2.z + a3.z;
            a0.w += a1.w + a2.w + a3.w;
            a0.x += __shfl_down(a0.x, 32);
            a0.y += __shfl_down(a0.y, 32);
            a0.z += __shfl_down(a0.z, 32);
            a0.w += __shfl_down(a0.w, 32);
            if (half == 0 && node < n) {
                float d = dis[node];
                float4 b = ld4(&bias[l32 * 4]);
                float4 oV = make_float4(d * a0.x + b.x, d * a0.y + b.y,
                                        d * a0.z + b.z, d * a0.w + b.w);
                uint2 w = make_uint2(pk2(oV.x, oV.y), pk2(oV.z, oV.w));
                reinterpret_cast<uint2*>(outv)[(size_t)node * 32 + l32] = w;
                if (STATS) {
                    st.x += oV.x; sq.x += oV.x * oV.x;
                    st.y += oV.y; sq.y += oV.y * oV.y;
                    st.z += oV.z; sq.z += oV.z * oV.z;
                    st.w += oV.w; sq.w += oV.w * oV.w;
                }
            }
        } else {
            const unsigned* hp = reinterpret_cast<const unsigned*>(hs);  // 32 u32/row
            float2 a0 = make_float2(0.f, 0.f);
            float2 a1 = a0, a2 = a0, a3 = a0;
            if (half == 0 && node < n) {
                unsigned w = hp[(size_t)node * 32 + l32];           // self-loop
                a0 = make_float2(bf_lo(w), bf_hi(w));
            }
            const int lim = e1 - 1;
            for (int e = e0; e < e1; e += 8) {
                int ee0 = e + 0 + half, ee1 = e + 2 + half;
                int ee2 = e + 4 + half, ee3 = e + 6 + half;
                int i0 = csr[ee0 <= lim ? ee0 : lim];
                int i1 = csr[ee1 <= lim ? ee1 : lim];
                int i2 = csr[ee2 <= lim ? ee2 : lim];
                int i3 = csr[ee3 <= lim ? ee3 : lim];
                unsigned w0 = hp[(size_t)i0 * 32 + l32];
                unsigned w1 = hp[(size_t)i1 * 32 + l32];
                unsigned w2 = hp[(size_t)i2 * 32 + l32];
                unsigned w3 = hp[(size_t)i3 * 32 + l32];
                if (ee0 < e1) { a0.x += bf_lo(w0); a0.y += bf_hi(w0); }
                if (ee1 < e1) { a1.x += bf_lo(w1); a1.y += bf_hi(w1); }
                if (ee2 < e1) { a2.x += bf_lo(w2); a2.y += bf_hi(w2); }
                if (ee3 < e1) { a3.x += bf_lo(w3); a3.y += bf_hi(w3); }
            }
            a0.x += a1.x + a2.x + a3.x;
            a0.y += a1.y + a2.y + a3.y;
            a0.x += __shfl_down(a0.x, 32);
            a0.y += __shfl_down(a0.y, 32);
            if (half == 0 && node < n) {
                float d = dis[node];
                float2 o = make_float2(d * a0.x + bias[l32 * 2],
                                       d * a0.y + bias[l32 * 2 + 1]);
                reinterpret_cast<float2*>(outv)[(size_t)node * 32 + l32] = o;
            }
        }
    }

    if constexpr (STATS) {
        __shared__ float ls[4][128];
        __shared__ float ls2[4][128];
        __shared__ int sIsLast;
        if (half == 0) {
            int c = l32 * 4;
            ls[wave][c + 0] = st.x; ls2[wave][c + 0] = sq.x;
            ls[wave][c + 1] = st.y; ls2[wave][c + 1] = sq.y;
            ls[wave][c + 2] = st.z; ls2[wave][c + 2] = sq.z;
            ls[wave][c + 3] = st.w; ls2[wave][c + 3] = sq.w;
        }
        __syncthreads();
        int t = threadIdx.x;
        int slot = (blockIdx.x & (NSLOT - 1)) * 128;
        if (t < 128) {
            atomicAdd(&ssum[slot + t], ls[0][t] + ls[1][t] + ls[2][t] + ls[3][t]);
        } else {
            int c = t - 128;
            atomicAdd(&ssq[slot + c], ls2[0][c] + ls2[1][c] + ls2[2][c] + ls2[3][c]);
        }
        // last finishing block computes BN affine params in-kernel
        __threadfence();
        if (t == 0) {
            int prev = __hip_atomic_fetch_add(counter, 1, __ATOMIC_ACQ_REL,
                                              __HIP_MEMORY_SCOPE_AGENT);
            sIsLast = (prev == (int)gridDim.x - 1) ? 1 : 0;
        }
        __syncthreads();
        if (sIsLast) {
            __threadfence();
            if (t < 128) {
                float s = 0.f, s2 = 0.f;
                for (int k = 0; k < NSLOT; ++k) {
                    s += __hip_atomic_load(&ssum[k * 128 + t], __ATOMIC_RELAXED,
                                           __HIP_MEMORY_SCOPE_AGENT);
                    s2 += __hip_atomic_load(&ssq[k * 128 + t], __ATOMIC_RELAXED,
                                            __HIP_MEMORY_SCOPE_AGENT);
                }
                float inv_n = 1.0f / (float)n;
                float mean = s * inv_n;
                float var = s2 * inv_n - mean * mean;
                float sc = gamma[t] * rsqrtf(var + 1e-5f);
                aOut[t] = sc;
                ccOut[t] = beta[t] - mean * sc;
            }
        }
    }
}

extern "C" void kernel_launch(void* const* d_in, const int* in_sizes, int n_in,
                              void* d_out, int out_size, void* d_ws, size_t ws_size,
                              hipStream_t stream) {
    const float* x      = (const float*)d_in[0];
    const int*   ei     = (const int*)d_in[1];     // [2,E] row-major: src then dst
    const float* W1     = (const float*)d_in[2];
    const float* b1     = (const float*)d_in[3];
    const float* gamma1 = (const float*)d_in[4];
    const float* beta1  = (const float*)d_in[5];
    const float* W2     = (const float*)d_in[6];
    const float* b2     = (const float*)d_in[7];
    const float* gamma2 = (const float*)d_in[8];
    const float* beta2  = (const float*)d_in[9];
    const float* W3     = (const float*)d_in[10];
    const float* b3     = (const float*)d_in[11];
    float* out = (float*)d_out;

    const int n = in_sizes[0] / 128;       // 50000
    const int e = in_sizes[1] / 2;         // 600000
    const int* esrc = ei;
    const int* edst = ei + e;

    // workspace layout (256B aligned chunks)
    char* p = (char*)d_ws;
    auto alloc = [&](size_t bytes) {
        void* r = p;
        p += (bytes + 255) & ~size_t(255);
        return r;
    };
    unsigned short* hbf  = (unsigned short*)alloc(sizeof(unsigned short) * (size_t)n * 128);
    unsigned short* bufB = (unsigned short*)alloc(sizeof(unsigned short) * (size_t)n * 128);
    int*   cnt    = (int*)alloc(sizeof(int) * n);
    int*   offs   = (int*)alloc(sizeof(int) * (n + 1));
    int*   cursor = (int*)alloc(sizeof(int) * n);
    int*   csr    = (int*)alloc(sizeof(int) * e);
    float* dis    = (float*)alloc(sizeof(float) * n);
    float* stats  = (float*)alloc(sizeof(float) * 4 * NSLOT * 128);
    float* bn     = (float*)alloc(sizeof(float) * 512);  // a1,cc1,a2,cc2
    int*   counters = (int*)alloc(sizeof(int) * 8);
    int*   chunkSum = (int*)alloc(sizeof(int) * NCHUNK);
    unsigned short* wf1 = (unsigned short*)alloc(sizeof(unsigned short) * 32 * 64 * 8);
    unsigned short* wf2 = (unsigned short*)alloc(sizeof(unsigned short) * 32 * 64 * 8);
    unsigned short* wf3 = (unsigned short*)alloc(sizeof(unsigned short) * 16 * 64 * 8);
    float* ssum1 = stats,                   *ssq1 = stats + NSLOT * 128;
    float* ssum2 = stats + 2 * NSLOT * 128, *ssq2 = stats + 3 * NSLOT * 128;
    float* a1 = bn, *cc1 = bn + 128, *a2 = bn + 256, *cc2 = bn + 384;

    int gb_n  = (n + 255) / 256;
    int gb_e  = (e + 255) / 256;
    int gb_gemm = (n + 31) / 32;
    int gb_agg = (n + 4 * NPW - 1) / (4 * NPW);

    // setup: init + W prep (merged), count, chunk-scan (2 kernels), scatter
    k_setup<<<gb_n + 20, 256, 0, stream>>>(cnt, stats, counters, n, gb_n, W1, W2, W3, wf1, wf2, wf3);
    k_count<<<gb_e, 256, 0, stream>>>(edst, cnt, e);
    k_chunksum<<<NCHUNK / 256, 256, 0, stream>>>(cnt, chunkSum, n);
    k_chunkwrite<<<NCHUNK / 256, 256, 0, stream>>>(cnt, chunkSum, offs, cursor, dis, n, e);
    k_scatter<<<gb_e, 256, 0, stream>>>(esrc, edst, cursor, csr, e);

    // layer 1 (agg's last block computes a1/cc1)
    k_gemm<false, 128, false><<<gb_gemm, 256, 0, stream>>>(x, (const uint4*)wf1, dis, nullptr, nullptr, hbf, n);
    k_agg<128, true><<<gb_agg, 256, 0, stream>>>(hbf, offs, csr, dis, b1, bufB,
                                                 ssum1, ssq1, gamma1, beta1, a1, cc1, &counters[0], n);

    // layer 2 (agg's last block computes a2/cc2)
    k_gemm<true, 128, true><<<gb_gemm, 256, 0, stream>>>(bufB, (const uint4*)wf2, dis, a1, cc1, hbf, n);
    k_agg<128, true><<<gb_agg, 256, 0, stream>>>(hbf, offs, csr, dis, b2, bufB,
                                                 ssum2, ssq2, gamma2, beta2, a2, cc2, &counters[1], n);

    // layer 3 (no BN/ReLU after; fp32 output to d_out)
    k_gemm<true, 64, true><<<gb_gemm, 256, 0, stream>>>(bufB, (const uint4*)wf3, dis, a2, cc2, hbf, n);
    k_agg<64, false><<<gb_agg, 256, 0, stream>>>(hbf, offs, csr, dis, b3, out,
                                                 nullptr, nullptr, nullptr, nullptr, nullptr, nullptr, &counters[2], n);
}

// Round 13
// 232.494 us; speedup vs baseline: 3.3633x; 3.3633x over previous
//
#include <hip/hip_runtime.h>
#include <hip/hip_bf16.h>

// GCN: 3 layers, N=50000 nodes, E=600000 edges, feats 128->128->128->64,
// BatchNorm+ReLU between layers. norm = dis[src]*dis[dst] factorized out.
// GEMMs on MFMA bf16 (fp32 accum); intermediate buffers bf16; BN stats fused
// into k_agg (register-accumulated over NPW nodes, one flush per block).
// Agg edge loop: branchless masked 8-wide (loads always issued, clamped
// indices; accumulates via 0/1-mask fmaf) -> 4 row-loads in flight, no tail.

#define NCHUNK 1024
#define NSLOT 64
#define NPW 4            // nodes per wave in k_agg

typedef short bf16x8 __attribute__((ext_vector_type(8)));
typedef float f32x4 __attribute__((ext_vector_type(4)));

union FragU { uint4 u; bf16x8 f; };

static __device__ __forceinline__ float4 ld4(const float* p) {
    return *reinterpret_cast<const float4*>(p);
}

// pack two fp32 -> bf16x2 (RNE), memory order lo,hi
static __device__ __forceinline__ unsigned pk2(float lo, float hi) {
    __hip_bfloat162 h = __float22bfloat162_rn(make_float2(lo, hi));
    union { __hip_bfloat162 h2; unsigned u; } c;
    c.h2 = h;
    return c.u;
}
static __device__ __forceinline__ unsigned short bf1(float v) {
    return (unsigned short)(pk2(v, 0.f) & 0xffffu);
}
static __device__ __forceinline__ float bf_lo(unsigned u) { return __uint_as_float(u << 16); }
static __device__ __forceinline__ float bf_hi(unsigned u) { return __uint_as_float(u & 0xffff0000u); }

// Merged: cnt/stats zero-init (blocks < gbInit) + W1/W2/W3 fragment prep
// (blocks >= gbInit; 4 64-lane units per 256-thread block).
// Frag f = t*4+kk; lane l holds B[k = kk*32+(l>>4)*8+j][col = t*16+(l&15)].
__global__ __launch_bounds__(256) void k_setup(int* __restrict__ cnt,
                                               float* __restrict__ stats, int n,
                                               int gbInit,
                                               const float* __restrict__ W1,
                                               const float* __restrict__ W2,
                                               const float* __restrict__ W3,
                                               unsigned short* __restrict__ wf1,
                                               unsigned short* __restrict__ wf2,
                                               unsigned short* __restrict__ wf3) {
    int b = blockIdx.x;
    if (b < gbInit) {
        int i = b * 256 + threadIdx.x;
        if (i < n) cnt[i] = 0;
        if (i < 4 * NSLOT * 128) stats[i] = 0.f;   // ssum1, ssq1, ssum2, ssq2
        return;
    }
    int unit = (b - gbInit) * 4 + (threadIdx.x >> 6);   // 0..79
    if (unit >= 80) return;
    int l = threadIdx.x & 63;
    const float* W; unsigned short* Wf; int NC; int blk;
    if (unit < 32)      { W = W1; Wf = wf1; NC = 128; blk = unit; }
    else if (unit < 64) { W = W2; Wf = wf2; NC = 128; blk = unit - 32; }
    else                { W = W3; Wf = wf3; NC = 64;  blk = unit - 64; }
    int kk = blk & 3;
    int col = (blk >> 2) * 16 + (l & 15);
    int k0 = kk * 32 + (l >> 4) * 8;
    unsigned short* dst = &Wf[((size_t)blk * 64 + l) * 8];
#pragma unroll
    for (int j = 0; j < 8; ++j)
        dst[j] = bf1(W[(size_t)(k0 + j) * NC + col]);
}

__global__ void k_count(const int* __restrict__ dst, int* __restrict__ cnt, int e) {
    int i = blockIdx.x * 256 + threadIdx.x;
    if (i < e) atomicAdd(&cnt[dst[i]], 1);
}

// Stage 1: per-chunk sums of cnt. NCHUNK threads across 4 blocks.
__global__ __launch_bounds__(256) void k_chunksum(const int* __restrict__ cnt,
                                                  int* __restrict__ chunkSum, int n) {
    int t = blockIdx.x * 256 + threadIdx.x;   // 0..NCHUNK-1
    int per = (n + NCHUNK - 1) / NCHUNK;
    int lo = t * per; if (lo > n) lo = n;
    int hi = lo + per; if (hi > n) hi = n;
    int s = 0;
    for (int i = lo; i < hi; ++i) s += cnt[i];
    chunkSum[t] = s;
}

// Stage 2: each of the 4 blocks redundantly scans all NCHUNK chunk sums in
// LDS (4 loads/thread + 256-scan), then writes offs/cursor/dis for its own
// 256 chunks.
__global__ __launch_bounds__(256) void k_chunkwrite(const int* __restrict__ cnt,
                                                    const int* __restrict__ chunkSum,
                                                    int* __restrict__ offs,
                                                    int* __restrict__ cursor,
                                                    float* __restrict__ dis,
                                                    int n, int e) {
    __shared__ int lbase[NCHUNK];
    __shared__ int lth[256];
    int t = threadIdx.x;
    int a0 = chunkSum[t * 4 + 0], a1 = chunkSum[t * 4 + 1];
    int a2 = chunkSum[t * 4 + 2], a3 = chunkSum[t * 4 + 3];
    lth[t] = a0 + a1 + a2 + a3;
    __syncthreads();
    for (int off = 1; off < 256; off <<= 1) {
        int v = (t >= off) ? lth[t - off] : 0;
        __syncthreads();
        lth[t] += v;
        __syncthreads();
    }
    int base = (t == 0) ? 0 : lth[t - 1];
    lbase[t * 4 + 0] = base;
    lbase[t * 4 + 1] = base + a0;
    lbase[t * 4 + 2] = base + a0 + a1;
    lbase[t * 4 + 3] = base + a0 + a1 + a2;
    __syncthreads();
    int cid = blockIdx.x * 256 + t;
    int per = (n + NCHUNK - 1) / NCHUNK;
    int lo = cid * per; if (lo > n) lo = n;
    int hi = lo + per; if (hi > n) hi = n;
    int run = lbase[cid];
    for (int i = lo; i < hi; ++i) {
        offs[i] = run;
        cursor[i] = run;
        int c = cnt[i];
        dis[i] = rsqrtf((float)(c + 1));
        run += c;
    }
    if (cid == 0) offs[n] = e;
}

__global__ void k_scatter(const int* __restrict__ src, const int* __restrict__ dst,
                          int* __restrict__ cursor, int* __restrict__ csr, int e) {
    int i = blockIdx.x * 256 + threadIdx.x;
    if (i < e) {
        int p = atomicAdd(&cursor[dst[i]], 1);
        csr[p] = src[i];
    }
}

// out[row][col] = bf16( dis[row] * sum_k in'(row,k) * W[k][col] )
// in'(row,k) = TRANS ? relu(in*ta[k]+tc[k]) : in.  INBF: input rows are bf16.
//
// MFMA 16x16x32 bf16. Block: 32 rows x NC cols, 256 threads = 4 waves.
// Wave w: rows (w>>1)*16..+16, col-half (w&1)*NC/2. A staged bf16 in LDS
// with XOR swizzle byte^=(row&7)<<4 (G4). B from pre-fragmented Wf.
// Epilogue: acc -> LDS [32][NC+8] (pad -> 2-way banks, free) -> coalesced
// uint4 row stores.
template <bool TRANS, int NC, bool INBF>
__global__ __launch_bounds__(256) void k_gemm(const void* __restrict__ inv,
                                              const uint4* __restrict__ Wf,
                                              const float* __restrict__ dis,
                                              const float* __restrict__ ta,
                                              const float* __restrict__ tc,
                                              unsigned short* __restrict__ out, int n) {
    constexpr int TPW = NC / 32;          // 16-col tiles per wave: 4 or 2
    constexpr int PADC = NC + 8;          // padded u16 row stride (16B-aligned)
    constexpr int SHN = (32 * PADC > 32 * 128) ? 32 * PADC : 32 * 128;
    __shared__ unsigned short sh[SHN];
    const int tid = threadIdx.x;
    const int row0 = blockIdx.x * 32;

    if constexpr (INBF) {
        const unsigned short* in = (const unsigned short*)inv;
#pragma unroll
        for (int it = 0; it < 2; ++it) {
            int flat = it * 256 + tid;
            int r = flat >> 4, j = flat & 15;     // j indexes uint4 (8 bf16)
            int grow = row0 + r;
            uint4 v = make_uint4(0, 0, 0, 0);
            if (grow < n) v = *reinterpret_cast<const uint4*>(&in[(size_t)grow * 128 + j * 8]);
            if (TRANS) {
                int f = j * 8;
                float4 A0 = ld4(&ta[f]), A1 = ld4(&ta[f + 4]);
                float4 C0 = ld4(&tc[f]), C1 = ld4(&tc[f + 4]);
                v.x = pk2(fmaxf(bf_lo(v.x) * A0.x + C0.x, 0.f),
                          fmaxf(bf_hi(v.x) * A0.y + C0.y, 0.f));
                v.y = pk2(fmaxf(bf_lo(v.y) * A0.z + C0.z, 0.f),
                          fmaxf(bf_hi(v.y) * A0.w + C0.w, 0.f));
                v.z = pk2(fmaxf(bf_lo(v.z) * A1.x + C1.x, 0.f),
                          fmaxf(bf_hi(v.z) * A1.y + C1.y, 0.f));
                v.w = pk2(fmaxf(bf_lo(v.w) * A1.z + C1.z, 0.f),
                          fmaxf(bf_hi(v.w) * A1.w + C1.w, 0.f));
            }
            int byte = r * 256 + ((j * 16) ^ ((r & 7) << 4));
            *reinterpret_cast<uint4*>(reinterpret_cast<char*>(sh) + byte) = v;
        }
    } else {
        const float* in = (const float*)inv;
#pragma unroll
        for (int it = 0; it < 4; ++it) {
            int flat = it * 256 + tid;
            int r = flat >> 5, j4 = flat & 31;
            int grow = row0 + r;
            float4 v = make_float4(0.f, 0.f, 0.f, 0.f);
            if (grow < n) v = ld4(&in[(size_t)grow * 128 + j4 * 4]);
            if (TRANS) {
                int f = j4 * 4;
                float4 A = ld4(&ta[f]);
                float4 C = ld4(&tc[f]);
                v.x = fmaxf(v.x * A.x + C.x, 0.f);
                v.y = fmaxf(v.y * A.y + C.y, 0.f);
                v.z = fmaxf(v.z * A.z + C.z, 0.f);
                v.w = fmaxf(v.w * A.w + C.w, 0.f);
            }
            int byte = r * 256 + ((j4 * 8) ^ ((r & 7) << 4));
            *reinterpret_cast<uint2*>(reinterpret_cast<char*>(sh) + byte) =
                make_uint2(pk2(v.x, v.y), pk2(v.z, v.w));
        }
    }
    __syncthreads();

    const int l = tid & 63, w = tid >> 6;
    const int l15 = l & 15, g = l >> 4;
    const int rhalf = (w >> 1) * 16;          // LDS row offset: 0 or 16
    const int tbase = (w & 1) * TPW;          // col-tile offset

    f32x4 acc[TPW];
#pragma unroll
    for (int t = 0; t < TPW; ++t) acc[t] = (f32x4){0.f, 0.f, 0.f, 0.f};

    const int arow = rhalf + l15;
    const char* xb = reinterpret_cast<const char*>(sh) + arow * 256;
    const int aswz = (arow & 7) << 4;

#pragma unroll
    for (int kk = 0; kk < 4; ++kk) {
        FragU a;
        a.u = *reinterpret_cast<const uint4*>(xb + ((kk * 64 + g * 16) ^ aswz));
#pragma unroll
        for (int t = 0; t < TPW; ++t) {
            FragU b;
            b.u = Wf[(size_t)((tbase + t) * 4 + kk) * 64 + l];
            acc[t] = __builtin_amdgcn_mfma_f32_16x16x32_bf16(a.f, b.f, acc[t], 0, 0, 0);
        }
    }

    // epilogue: D[row = g*4+r][col = l15] per tile -> LDS -> coalesced stores
    const int rbase = row0 + rhalf + g * 4;
    float dv[4];
#pragma unroll
    for (int r = 0; r < 4; ++r) {
        int rr = rbase + r;
        dv[r] = (rr < n) ? dis[rr] : 0.f;
    }
    __syncthreads();   // all waves done reading staged A before overwrite
#pragma unroll
    for (int t = 0; t < TPW; ++t) {
        int col = (tbase + t) * 16 + l15;
#pragma unroll
        for (int r = 0; r < 4; ++r) {
            int lrow = rhalf + g * 4 + r;
            sh[lrow * PADC + col] = bf1(acc[t][r] * dv[r]);
        }
    }
    __syncthreads();
    constexpr int U4R = NC / 8;           // uint4 per output row
#pragma unroll
    for (int it = 0; it < (32 * U4R) / 256; ++it) {
        int flat = it * 256 + tid;
        int row = flat / U4R, j = flat % U4R;
        int grow = row0 + row;
        if (grow < n) {
            uint4 v = *reinterpret_cast<const uint4*>(&sh[row * PADC + j * 8]);
            *reinterpret_cast<uint4*>(&out[(size_t)grow * NC + j * 8]) = v;
        }
    }
}

// h[i] = dis[i] * (hs[i] + sum_{src in(i)} hs[src]) + bias.  hs bf16.
// Each wave processes NPW consecutive nodes. Edge loop: branchless masked
// 8-wide — loads ALWAYS issued (indices clamped to lim), accumulate via
// fmaf with 0/1 mask. No control flow around loads -> 4 rows in flight.
// NC=128: 32 lanes x uint2 per row, 2 edges/step via half; writes bf16;
// BN stats in registers, one LDS+atomic flush per block.
// NC=64: one uint per lane; fp32 out, no stats.
template <int NC, bool STATS>
__global__ __launch_bounds__(256) void k_agg(const unsigned short* __restrict__ hs,
                                             const int* __restrict__ offs,
                                             const int* __restrict__ csr,
                                             const float* __restrict__ dis,
                                             const float* __restrict__ bias,
                                             void* __restrict__ outv,
                                             float* __restrict__ ssum,
                                             float* __restrict__ ssq, int n) {
    const int wave = threadIdx.x >> 6, lane = threadIdx.x & 63;
    const int half = lane >> 5, l32 = lane & 31;
    const int nodeBase = blockIdx.x * (4 * NPW) + wave * NPW;

    float4 st = make_float4(0.f, 0.f, 0.f, 0.f);   // stats: sum (half==0)
    float4 sq = make_float4(0.f, 0.f, 0.f, 0.f);   // stats: sumsq

    for (int j = 0; j < NPW; ++j) {
        const int node = nodeBase + j;
        int e0 = 0, e1 = 0;
        if (node < n) { e0 = offs[node]; e1 = offs[node + 1]; }

        if (NC == 128) {
            const uint2* hp = reinterpret_cast<const uint2*>(hs);  // 32 uint2/row
            float4 a0 = make_float4(0.f, 0.f, 0.f, 0.f);
            float4 a1 = a0, a2 = a0, a3 = a0;
            if (half == 0 && node < n) {
                uint2 w = hp[(size_t)node * 32 + l32];             // self-loop
                a0 = make_float4(bf_lo(w.x), bf_hi(w.x), bf_lo(w.y), bf_hi(w.y));
            }
            const int lim = e1 - 1;
            for (int e = e0; e < e1; e += 8) {
                int ee0 = e + 0 + half, ee1 = e + 2 + half;
                int ee2 = e + 4 + half, ee3 = e + 6 + half;
                float m0 = (ee0 < e1) ? 1.f : 0.f;
                float m1 = (ee1 < e1) ? 1.f : 0.f;
                float m2 = (ee2 < e1) ? 1.f : 0.f;
                float m3 = (ee3 < e1) ? 1.f : 0.f;
                int i0 = csr[ee0 <= lim ? ee0 : lim];
                int i1 = csr[ee1 <= lim ? ee1 : lim];
                int i2 = csr[ee2 <= lim ? ee2 : lim];
                int i3 = csr[ee3 <= lim ? ee3 : lim];
                uint2 w0 = hp[(size_t)i0 * 32 + l32];
                uint2 w1 = hp[(size_t)i1 * 32 + l32];
                uint2 w2 = hp[(size_t)i2 * 32 + l32];
                uint2 w3 = hp[(size_t)i3 * 32 + l32];
                a0.x = fmaf(m0, bf_lo(w0.x), a0.x);
                a0.y = fmaf(m0, bf_hi(w0.x), a0.y);
                a0.z = fmaf(m0, bf_lo(w0.y), a0.z);
                a0.w = fmaf(m0, bf_hi(w0.y), a0.w);
                a1.x = fmaf(m1, bf_lo(w1.x), a1.x);
                a1.y = fmaf(m1, bf_hi(w1.x), a1.y);
                a1.z = fmaf(m1, bf_lo(w1.y), a1.z);
                a1.w = fmaf(m1, bf_hi(w1.y), a1.w);
                a2.x = fmaf(m2, bf_lo(w2.x), a2.x);
                a2.y = fmaf(m2, bf_hi(w2.x), a2.y);
                a2.z = fmaf(m2, bf_lo(w2.y), a2.z);
                a2.w = fmaf(m2, bf_hi(w2.y), a2.w);
                a3.x = fmaf(m3, bf_lo(w3.x), a3.x);
                a3.y = fmaf(m3, bf_hi(w3.x), a3.y);
                a3.z = fmaf(m3, bf_lo(w3.y), a3.z);
                a3.w = fmaf(m3, bf_hi(w3.y), a3.w);
            }
            a0.x += a1.x + a2.x + a3.x;
            a0.y += a1.y + a2.y + a3.y;
            a0.z += a1.z + a2.z + a3.z;
            a0.w += a1.w + a2.w + a3.w;
            a0.x += __shfl_down(a0.x, 32);
            a0.y += __shfl_down(a0.y, 32);
            a0.z += __shfl_down(a0.z, 32);
            a0.w += __shfl_down(a0.w, 32);
            if (half == 0 && node < n) {
                float d = dis[node];
                float4 b = ld4(&bias[l32 * 4]);
                float4 oV = make_float4(d * a0.x + b.x, d * a0.y + b.y,
                                        d * a0.z + b.z, d * a0.w + b.w);
                uint2 w = make_uint2(pk2(oV.x, oV.y), pk2(oV.z, oV.w));
                reinterpret_cast<uint2*>(outv)[(size_t)node * 32 + l32] = w;
                if (STATS) {
                    st.x += oV.x; sq.x += oV.x * oV.x;
                    st.y += oV.y; sq.y += oV.y * oV.y;
                    st.z += oV.z; sq.z += oV.z * oV.z;
                    st.w += oV.w; sq.w += oV.w * oV.w;
                }
            }
        } else {
            const unsigned* hp = reinterpret_cast<const unsigned*>(hs);  // 32 u32/row
            float2 a0 = make_float2(0.f, 0.f);
            float2 a1 = a0, a2 = a0, a3 = a0;
            if (half == 0 && node < n) {
                unsigned w = hp[(size_t)node * 32 + l32];           // self-loop
                a0 = make_float2(bf_lo(w), bf_hi(w));
            }
            const int lim = e1 - 1;
            for (int e = e0; e < e1; e += 8) {
                int ee0 = e + 0 + half, ee1 = e + 2 + half;
                int ee2 = e + 4 + half, ee3 = e + 6 + half;
                float m0 = (ee0 < e1) ? 1.f : 0.f;
                float m1 = (ee1 < e1) ? 1.f : 0.f;
                float m2 = (ee2 < e1) ? 1.f : 0.f;
                float m3 = (ee3 < e1) ? 1.f : 0.f;
                int i0 = csr[ee0 <= lim ? ee0 : lim];
                int i1 = csr[ee1 <= lim ? ee1 : lim];
                int i2 = csr[ee2 <= lim ? ee2 : lim];
                int i3 = csr[ee3 <= lim ? ee3 : lim];
                unsigned w0 = hp[(size_t)i0 * 32 + l32];
                unsigned w1 = hp[(size_t)i1 * 32 + l32];
                unsigned w2 = hp[(size_t)i2 * 32 + l32];
                unsigned w3 = hp[(size_t)i3 * 32 + l32];
                a0.x = fmaf(m0, bf_lo(w0), a0.x);
                a0.y = fmaf(m0, bf_hi(w0), a0.y);
                a1.x = fmaf(m1, bf_lo(w1), a1.x);
                a1.y = fmaf(m1, bf_hi(w1), a1.y);
                a2.x = fmaf(m2, bf_lo(w2), a2.x);
                a2.y = fmaf(m2, bf_hi(w2), a2.y);
                a3.x = fmaf(m3, bf_lo(w3), a3.x);
                a3.y = fmaf(m3, bf_hi(w3), a3.y);
            }
            a0.x += a1.x + a2.x + a3.x;
            a0.y += a1.y + a2.y + a3.y;
            a0.x += __shfl_down(a0.x, 32);
            a0.y += __shfl_down(a0.y, 32);
            if (half == 0 && node < n) {
                float d = dis[node];
                float2 o = make_float2(d * a0.x + bias[l32 * 2],
                                       d * a0.y + bias[l32 * 2 + 1]);
                reinterpret_cast<float2*>(outv)[(size_t)node * 32 + l32] = o;
            }
        }
    }

    if constexpr (STATS) {
        __shared__ float ls[4][128];
        __shared__ float ls2[4][128];
        if (half == 0) {
            int c = l32 * 4;
            ls[wave][c + 0] = st.x; ls2[wave][c + 0] = sq.x;
            ls[wave][c + 1] = st.y; ls2[wave][c + 1] = sq.y;
            ls[wave][c + 2] = st.z; ls2[wave][c + 2] = sq.z;
            ls[wave][c + 3] = st.w; ls2[wave][c + 3] = sq.w;
        }
        __syncthreads();
        int t = threadIdx.x;
        int slot = (blockIdx.x & (NSLOT - 1)) * 128;
        if (t < 128) {
            atomicAdd(&ssum[slot + t], ls[0][t] + ls[1][t] + ls[2][t] + ls[3][t]);
        } else {
            int c = t - 128;
            atomicAdd(&ssq[slot + c], ls2[0][c] + ls2[1][c] + ls2[2][c] + ls2[3][c]);
        }
    }
}

// Reduce NSLOT partials -> BN affine params a, cc.
__global__ void k_bnparams(const float* __restrict__ ssum, const float* __restrict__ ssq,
                           const float* __restrict__ gamma, const float* __restrict__ beta,
                           float* __restrict__ a, float* __restrict__ cc, int n) {
    int c = threadIdx.x;
    if (c < 128) {
        float s = 0.f, s2 = 0.f;
        for (int k = 0; k < NSLOT; ++k) {
            s += ssum[k * 128 + c];
            s2 += ssq[k * 128 + c];
        }
        float inv_n = 1.0f / (float)n;
        float mean = s * inv_n;
        float var = s2 * inv_n - mean * mean;
        float sc = gamma[c] * rsqrtf(var + 1e-5f);
        a[c] = sc;
        cc[c] = beta[c] - mean * sc;
    }
}

extern "C" void kernel_launch(void* const* d_in, const int* in_sizes, int n_in,
                              void* d_out, int out_size, void* d_ws, size_t ws_size,
                              hipStream_t stream) {
    const float* x      = (const float*)d_in[0];
    const int*   ei     = (const int*)d_in[1];     // [2,E] row-major: src then dst
    const float* W1     = (const float*)d_in[2];
    const float* b1     = (const float*)d_in[3];
    const float* gamma1 = (const float*)d_in[4];
    const float* beta1  = (const float*)d_in[5];
    const float* W2     = (const float*)d_in[6];
    const float* b2     = (const float*)d_in[7];
    const float* gamma2 = (const float*)d_in[8];
    const float* beta2  = (const float*)d_in[9];
    const float* W3     = (const float*)d_in[10];
    const float* b3     = (const float*)d_in[11];
    float* out = (float*)d_out;

    const int n = in_sizes[0] / 128;       // 50000
    const int e = in_sizes[1] / 2;         // 600000
    const int* esrc = ei;
    const int* edst = ei + e;

    // workspace layout (256B aligned chunks)
    char* p = (char*)d_ws;
    auto alloc = [&](size_t bytes) {
        void* r = p;
        p += (bytes + 255) & ~size_t(255);
        return r;
    };
    unsigned short* hbf  = (unsigned short*)alloc(sizeof(unsigned short) * (size_t)n * 128);
    unsigned short* bufB = (unsigned short*)alloc(sizeof(unsigned short) * (size_t)n * 128);
    int*   cnt    = (int*)alloc(sizeof(int) * n);
    int*   offs   = (int*)alloc(sizeof(int) * (n + 1));
    int*   cursor = (int*)alloc(sizeof(int) * n);
    int*   csr    = (int*)alloc(sizeof(int) * e);
    float* dis    = (float*)alloc(sizeof(float) * n);
    float* stats  = (float*)alloc(sizeof(float) * 4 * NSLOT * 128);
    float* bn     = (float*)alloc(sizeof(float) * 512);  // a1,cc1,a2,cc2
    int*   chunkSum = (int*)alloc(sizeof(int) * NCHUNK);
    unsigned short* wf1 = (unsigned short*)alloc(sizeof(unsigned short) * 32 * 64 * 8);
    unsigned short* wf2 = (unsigned short*)alloc(sizeof(unsigned short) * 32 * 64 * 8);
    unsigned short* wf3 = (unsigned short*)alloc(sizeof(unsigned short) * 16 * 64 * 8);
    float* ssum1 = stats,                   *ssq1 = stats + NSLOT * 128;
    float* ssum2 = stats + 2 * NSLOT * 128, *ssq2 = stats + 3 * NSLOT * 128;
    float* a1 = bn, *cc1 = bn + 128, *a2 = bn + 256, *cc2 = bn + 384;

    int gb_n  = (n + 255) / 256;
    int gb_e  = (e + 255) / 256;
    int gb_gemm = (n + 31) / 32;
    int gb_agg = (n + 4 * NPW - 1) / (4 * NPW);

    // setup: init + W prep (merged), count, chunk-scan (2 kernels), scatter
    k_setup<<<gb_n + 20, 256, 0, stream>>>(cnt, stats, n, gb_n, W1, W2, W3, wf1, wf2, wf3);
    k_count<<<gb_e, 256, 0, stream>>>(edst, cnt, e);
    k_chunksum<<<NCHUNK / 256, 256, 0, stream>>>(cnt, chunkSum, n);
    k_chunkwrite<<<NCHUNK / 256, 256, 0, stream>>>(cnt, chunkSum, offs, cursor, dis, n, e);
    k_scatter<<<gb_e, 256, 0, stream>>>(esrc, edst, cursor, csr, e);

    // layer 1
    k_gemm<false, 128, false><<<gb_gemm, 256, 0, stream>>>(x, (const uint4*)wf1, dis, nullptr, nullptr, hbf, n);
    k_agg<128, true><<<gb_agg, 256, 0, stream>>>(hbf, offs, csr, dis, b1, bufB, ssum1, ssq1, n);
    k_bnparams<<<1, 128, 0, stream>>>(ssum1, ssq1, gamma1, beta1, a1, cc1, n);

    // layer 2
    k_gemm<true, 128, true><<<gb_gemm, 256, 0, stream>>>(bufB, (const uint4*)wf2, dis, a1, cc1, hbf, n);
    k_agg<128, true><<<gb_agg, 256, 0, stream>>>(hbf, offs, csr, dis, b2, bufB, ssum2, ssq2, n);
    k_bnparams<<<1, 128, 0, stream>>>(ssum2, ssq2, gamma2, beta2, a2, cc2, n);

    // layer 3 (no BN/ReLU after; fp32 output to d_out)
    k_gemm<true, 64, true><<<gb_gemm, 256, 0, stream>>>(bufB, (const uint4*)wf3, dis, a2, cc2, hbf, n);
    k_agg<64, false><<<gb_agg, 256, 0, stream>>>(hbf, offs, csr, dis, b3, out, nullptr, nullptr, n);
}

// Round 14
// 229.170 us; speedup vs baseline: 3.4120x; 1.0145x over previous
//
#include <hip/hip_runtime.h>
#include <hip/hip_bf16.h>

// GCN: 3 layers, N=50000 nodes, E=600000 edges, feats 128->128->128->64,
// BatchNorm+ReLU between layers. norm = dis[src]*dis[dst] factorized out.
// GEMMs on MFMA bf16 (fp32 accum), 64-row blocks (32 MFMA/wave/barrier);
// intermediate buffers bf16; BN stats fused into k_agg (register-accumulated
// over NPW nodes, one flush per block). Agg edge loop: branchless masked
// 8-wide (loads always issued, clamped indices; fmaf 0/1 mask) -> no tail.

#define NCHUNK 1024
#define NSLOT 64
#define NPW 4            // nodes per wave in k_agg

typedef short bf16x8 __attribute__((ext_vector_type(8)));
typedef float f32x4 __attribute__((ext_vector_type(4)));

union FragU { uint4 u; bf16x8 f; };

static __device__ __forceinline__ float4 ld4(const float* p) {
    return *reinterpret_cast<const float4*>(p);
}

// pack two fp32 -> bf16x2 (RNE), memory order lo,hi
static __device__ __forceinline__ unsigned pk2(float lo, float hi) {
    __hip_bfloat162 h = __float22bfloat162_rn(make_float2(lo, hi));
    union { __hip_bfloat162 h2; unsigned u; } c;
    c.h2 = h;
    return c.u;
}
static __device__ __forceinline__ unsigned short bf1(float v) {
    return (unsigned short)(pk2(v, 0.f) & 0xffffu);
}
static __device__ __forceinline__ float bf_lo(unsigned u) { return __uint_as_float(u << 16); }
static __device__ __forceinline__ float bf_hi(unsigned u) { return __uint_as_float(u & 0xffff0000u); }

// Merged: cnt/stats zero-init (blocks < gbInit) + W1/W2/W3 fragment prep
// (blocks >= gbInit; 4 64-lane units per 256-thread block).
// Frag f = t*4+kk; lane l holds B[k = kk*32+(l>>4)*8+j][col = t*16+(l&15)].
__global__ __launch_bounds__(256) void k_setup(int* __restrict__ cnt,
                                               float* __restrict__ stats, int n,
                                               int gbInit,
                                               const float* __restrict__ W1,
                                               const float* __restrict__ W2,
                                               const float* __restrict__ W3,
                                               unsigned short* __restrict__ wf1,
                                               unsigned short* __restrict__ wf2,
                                               unsigned short* __restrict__ wf3) {
    int b = blockIdx.x;
    if (b < gbInit) {
        int i = b * 256 + threadIdx.x;
        if (i < n) cnt[i] = 0;
        if (i < 4 * NSLOT * 128) stats[i] = 0.f;   // ssum1, ssq1, ssum2, ssq2
        return;
    }
    int unit = (b - gbInit) * 4 + (threadIdx.x >> 6);   // 0..79
    if (unit >= 80) return;
    int l = threadIdx.x & 63;
    const float* W; unsigned short* Wf; int NC; int blk;
    if (unit < 32)      { W = W1; Wf = wf1; NC = 128; blk = unit; }
    else if (unit < 64) { W = W2; Wf = wf2; NC = 128; blk = unit - 32; }
    else                { W = W3; Wf = wf3; NC = 64;  blk = unit - 64; }
    int kk = blk & 3;
    int col = (blk >> 2) * 16 + (l & 15);
    int k0 = kk * 32 + (l >> 4) * 8;
    unsigned short* dst = &Wf[((size_t)blk * 64 + l) * 8];
#pragma unroll
    for (int j = 0; j < 8; ++j)
        dst[j] = bf1(W[(size_t)(k0 + j) * NC + col]);
}

__global__ void k_count(const int* __restrict__ dst, int* __restrict__ cnt, int e) {
    int i = blockIdx.x * 256 + threadIdx.x;
    if (i < e) atomicAdd(&cnt[dst[i]], 1);
}

// Stage 1: per-chunk sums of cnt. NCHUNK threads across 4 blocks.
__global__ __launch_bounds__(256) void k_chunksum(const int* __restrict__ cnt,
                                                  int* __restrict__ chunkSum, int n) {
    int t = blockIdx.x * 256 + threadIdx.x;   // 0..NCHUNK-1
    int per = (n + NCHUNK - 1) / NCHUNK;
    int lo = t * per; if (lo > n) lo = n;
    int hi = lo + per; if (hi > n) hi = n;
    int s = 0;
    for (int i = lo; i < hi; ++i) s += cnt[i];
    chunkSum[t] = s;
}

// Stage 2: each of the 4 blocks redundantly scans all NCHUNK chunk sums in
// LDS (4 loads/thread + 256-scan), then writes offs/cursor/dis for its own
// 256 chunks.
__global__ __launch_bounds__(256) void k_chunkwrite(const int* __restrict__ cnt,
                                                    const int* __restrict__ chunkSum,
                                                    int* __restrict__ offs,
                                                    int* __restrict__ cursor,
                                                    float* __restrict__ dis,
                                                    int n, int e) {
    __shared__ int lbase[NCHUNK];
    __shared__ int lth[256];
    int t = threadIdx.x;
    int a0 = chunkSum[t * 4 + 0], a1 = chunkSum[t * 4 + 1];
    int a2 = chunkSum[t * 4 + 2], a3 = chunkSum[t * 4 + 3];
    lth[t] = a0 + a1 + a2 + a3;
    __syncthreads();
    for (int off = 1; off < 256; off <<= 1) {
        int v = (t >= off) ? lth[t - off] : 0;
        __syncthreads();
        lth[t] += v;
        __syncthreads();
    }
    int base = (t == 0) ? 0 : lth[t - 1];
    lbase[t * 4 + 0] = base;
    lbase[t * 4 + 1] = base + a0;
    lbase[t * 4 + 2] = base + a0 + a1;
    lbase[t * 4 + 3] = base + a0 + a1 + a2;
    __syncthreads();
    int cid = blockIdx.x * 256 + t;
    int per = (n + NCHUNK - 1) / NCHUNK;
    int lo = cid * per; if (lo > n) lo = n;
    int hi = lo + per; if (hi > n) hi = n;
    int run = lbase[cid];
    for (int i = lo; i < hi; ++i) {
        offs[i] = run;
        cursor[i] = run;
        int c = cnt[i];
        dis[i] = rsqrtf((float)(c + 1));
        run += c;
    }
    if (cid == 0) offs[n] = e;
}

__global__ void k_scatter(const int* __restrict__ src, const int* __restrict__ dst,
                          int* __restrict__ cursor, int* __restrict__ csr, int e) {
    int i = blockIdx.x * 256 + threadIdx.x;
    if (i < e) {
        int p = atomicAdd(&cursor[dst[i]], 1);
        csr[p] = src[i];
    }
}

// out[row][col] = bf16( dis[row] * sum_k in'(row,k) * W[k][col] )
// in'(row,k) = TRANS ? relu(in*ta[k]+tc[k]) : in.  INBF: input rows are bf16.
//
// MFMA 16x16x32 bf16. Block: 64 rows x NC cols, 256 threads = 4 waves.
// Wave w owns rows w*16..w*16+16, ALL NC cols (TPW = NC/16 col-tiles,
// 32 MFMA per wave per block). A staged bf16 in LDS with XOR swizzle
// byte^=(row&7)<<4 (G4). B from pre-fragmented Wf (same lines for all 4
// waves -> L2 broadcast). Epilogue: acc -> LDS [64][NC+8] -> coalesced
// uint4 row stores.
template <bool TRANS, int NC, bool INBF>
__global__ __launch_bounds__(256) void k_gemm(const void* __restrict__ inv,
                                              const uint4* __restrict__ Wf,
                                              const float* __restrict__ dis,
                                              const float* __restrict__ ta,
                                              const float* __restrict__ tc,
                                              unsigned short* __restrict__ out, int n) {
    constexpr int TPW = NC / 16;          // 16-col tiles per wave: 8 or 4
    constexpr int PADC = NC + 8;          // padded u16 row stride (16B-aligned)
    constexpr int SHN = (64 * PADC > 64 * 128) ? 64 * PADC : 64 * 128;
    __shared__ unsigned short sh[SHN];
    const int tid = threadIdx.x;
    const int row0 = blockIdx.x * 64;

    if constexpr (INBF) {
        const unsigned short* in = (const unsigned short*)inv;
#pragma unroll
        for (int it = 0; it < 4; ++it) {
            int flat = it * 256 + tid;            // 1024 uint4 = 64 rows x 16
            int r = flat >> 4, j = flat & 15;     // j indexes uint4 (8 bf16)
            int grow = row0 + r;
            uint4 v = make_uint4(0, 0, 0, 0);
            if (grow < n) v = *reinterpret_cast<const uint4*>(&in[(size_t)grow * 128 + j * 8]);
            if (TRANS) {
                int f = j * 8;
                float4 A0 = ld4(&ta[f]), A1 = ld4(&ta[f + 4]);
                float4 C0 = ld4(&tc[f]), C1 = ld4(&tc[f + 4]);
                v.x = pk2(fmaxf(bf_lo(v.x) * A0.x + C0.x, 0.f),
                          fmaxf(bf_hi(v.x) * A0.y + C0.y, 0.f));
                v.y = pk2(fmaxf(bf_lo(v.y) * A0.z + C0.z, 0.f),
                          fmaxf(bf_hi(v.y) * A0.w + C0.w, 0.f));
                v.z = pk2(fmaxf(bf_lo(v.z) * A1.x + C1.x, 0.f),
                          fmaxf(bf_hi(v.z) * A1.y + C1.y, 0.f));
                v.w = pk2(fmaxf(bf_lo(v.w) * A1.z + C1.z, 0.f),
                          fmaxf(bf_hi(v.w) * A1.w + C1.w, 0.f));
            }
            int byte = r * 256 + ((j * 16) ^ ((r & 7) << 4));
            *reinterpret_cast<uint4*>(reinterpret_cast<char*>(sh) + byte) = v;
        }
    } else {
        const float* in = (const float*)inv;
#pragma unroll
        for (int it = 0; it < 8; ++it) {
            int flat = it * 256 + tid;            // 2048 float4 = 64 rows x 32
            int r = flat >> 5, j4 = flat & 31;
            int grow = row0 + r;
            float4 v = make_float4(0.f, 0.f, 0.f, 0.f);
            if (grow < n) v = ld4(&in[(size_t)grow * 128 + j4 * 4]);
            if (TRANS) {
                int f = j4 * 4;
                float4 A = ld4(&ta[f]);
                float4 C = ld4(&tc[f]);
                v.x = fmaxf(v.x * A.x + C.x, 0.f);
                v.y = fmaxf(v.y * A.y + C.y, 0.f);
                v.z = fmaxf(v.z * A.z + C.z, 0.f);
                v.w = fmaxf(v.w * A.w + C.w, 0.f);
            }
            int byte = r * 256 + ((j4 * 8) ^ ((r & 7) << 4));
            *reinterpret_cast<uint2*>(reinterpret_cast<char*>(sh) + byte) =
                make_uint2(pk2(v.x, v.y), pk2(v.z, v.w));
        }
    }
    __syncthreads();

    const int l = tid & 63, w = tid >> 6;
    const int l15 = l & 15, g = l >> 4;
    const int rw0 = w * 16;                   // wave's 16-row slab in LDS

    f32x4 acc[TPW];
#pragma unroll
    for (int t = 0; t < TPW; ++t) acc[t] = (f32x4){0.f, 0.f, 0.f, 0.f};

    const int arow = rw0 + l15;
    const char* xb = reinterpret_cast<const char*>(sh) + arow * 256;
    const int aswz = (arow & 7) << 4;

#pragma unroll
    for (int kk = 0; kk < 4; ++kk) {
        FragU a;
        a.u = *reinterpret_cast<const uint4*>(xb + ((kk * 64 + g * 16) ^ aswz));
#pragma unroll
        for (int t = 0; t < TPW; ++t) {
            FragU b;
            b.u = Wf[(size_t)(t * 4 + kk) * 64 + l];
            acc[t] = __builtin_amdgcn_mfma_f32_16x16x32_bf16(a.f, b.f, acc[t], 0, 0, 0);
        }
    }

    // epilogue: D[row = g*4+r][col = l15] per tile -> LDS -> coalesced stores
    const int rbase = row0 + rw0 + g * 4;
    float dv[4];
#pragma unroll
    for (int r = 0; r < 4; ++r) {
        int rr = rbase + r;
        dv[r] = (rr < n) ? dis[rr] : 0.f;
    }
    __syncthreads();   // all waves done reading staged A before overwrite
#pragma unroll
    for (int t = 0; t < TPW; ++t) {
        int col = t * 16 + l15;
#pragma unroll
        for (int r = 0; r < 4; ++r) {
            int lrow = rw0 + g * 4 + r;
            sh[lrow * PADC + col] = bf1(acc[t][r] * dv[r]);
        }
    }
    __syncthreads();
    constexpr int U4R = NC / 8;           // uint4 per output row (16 or 8)
#pragma unroll
    for (int it = 0; it < (64 * U4R) / 256; ++it) {
        int flat = it * 256 + tid;
        int row = flat / U4R, j = flat % U4R;
        int grow = row0 + row;
        if (grow < n) {
            uint4 v = *reinterpret_cast<const uint4*>(&sh[row * PADC + j * 8]);
            *reinterpret_cast<uint4*>(&out[(size_t)grow * NC + j * 8]) = v;
        }
    }
}

// h[i] = dis[i] * (hs[i] + sum_{src in(i)} hs[src]) + bias.  hs bf16.
// Each wave processes NPW consecutive nodes. Edge loop: branchless masked
// 8-wide — loads ALWAYS issued (indices clamped to lim), accumulate via
// fmaf with 0/1 mask. No control flow around loads -> 4 rows in flight.
// NC=128: 32 lanes x uint2 per row, 2 edges/step via half; writes bf16;
// BN stats in registers, one LDS+atomic flush per block.
// NC=64: one uint per lane; fp32 out, no stats.
template <int NC, bool STATS>
__global__ __launch_bounds__(256) void k_agg(const unsigned short* __restrict__ hs,
                                             const int* __restrict__ offs,
                                             const int* __restrict__ csr,
                                             const float* __restrict__ dis,
                                             const float* __restrict__ bias,
                                             void* __restrict__ outv,
                                             float* __restrict__ ssum,
                                             float* __restrict__ ssq, int n) {
    const int wave = threadIdx.x >> 6, lane = threadIdx.x & 63;
    const int half = lane >> 5, l32 = lane & 31;
    const int nodeBase = blockIdx.x * (4 * NPW) + wave * NPW;

    float4 st = make_float4(0.f, 0.f, 0.f, 0.f);   // stats: sum (half==0)
    float4 sq = make_float4(0.f, 0.f, 0.f, 0.f);   // stats: sumsq

    for (int j = 0; j < NPW; ++j) {
        const int node = nodeBase + j;
        int e0 = 0, e1 = 0;
        if (node < n) { e0 = offs[node]; e1 = offs[node + 1]; }

        if (NC == 128) {
            const uint2* hp = reinterpret_cast<const uint2*>(hs);  // 32 uint2/row
            float4 a0 = make_float4(0.f, 0.f, 0.f, 0.f);
            float4 a1 = a0, a2 = a0, a3 = a0;
            if (half == 0 && node < n) {
                uint2 w = hp[(size_t)node * 32 + l32];             // self-loop
                a0 = make_float4(bf_lo(w.x), bf_hi(w.x), bf_lo(w.y), bf_hi(w.y));
            }
            const int lim = e1 - 1;
            for (int e = e0; e < e1; e += 8) {
                int ee0 = e + 0 + half, ee1 = e + 2 + half;
                int ee2 = e + 4 + half, ee3 = e + 6 + half;
                float m0 = (ee0 < e1) ? 1.f : 0.f;
                float m1 = (ee1 < e1) ? 1.f : 0.f;
                float m2 = (ee2 < e1) ? 1.f : 0.f;
                float m3 = (ee3 < e1) ? 1.f : 0.f;
                int i0 = csr[ee0 <= lim ? ee0 : lim];
                int i1 = csr[ee1 <= lim ? ee1 : lim];
                int i2 = csr[ee2 <= lim ? ee2 : lim];
                int i3 = csr[ee3 <= lim ? ee3 : lim];
                uint2 w0 = hp[(size_t)i0 * 32 + l32];
                uint2 w1 = hp[(size_t)i1 * 32 + l32];
                uint2 w2 = hp[(size_t)i2 * 32 + l32];
                uint2 w3 = hp[(size_t)i3 * 32 + l32];
                a0.x = fmaf(m0, bf_lo(w0.x), a0.x);
                a0.y = fmaf(m0, bf_hi(w0.x), a0.y);
                a0.z = fmaf(m0, bf_lo(w0.y), a0.z);
                a0.w = fmaf(m0, bf_hi(w0.y), a0.w);
                a1.x = fmaf(m1, bf_lo(w1.x), a1.x);
                a1.y = fmaf(m1, bf_hi(w1.x), a1.y);
                a1.z = fmaf(m1, bf_lo(w1.y), a1.z);
                a1.w = fmaf(m1, bf_hi(w1.y), a1.w);
                a2.x = fmaf(m2, bf_lo(w2.x), a2.x);
                a2.y = fmaf(m2, bf_hi(w2.x), a2.y);
                a2.z = fmaf(m2, bf_lo(w2.y), a2.z);
                a2.w = fmaf(m2, bf_hi(w2.y), a2.w);
                a3.x = fmaf(m3, bf_lo(w3.x), a3.x);
                a3.y = fmaf(m3, bf_hi(w3.x), a3.y);
                a3.z = fmaf(m3, bf_lo(w3.y), a3.z);
                a3.w = fmaf(m3, bf_hi(w3.y), a3.w);
            }
            a0.x += a1.x + a2.x + a3.x;
            a0.y += a1.y + a2.y + a3.y;
            a0.z += a1.z + a2.z + a3.z;
            a0.w += a1.w + a2.w + a3.w;
            a0.x += __shfl_down(a0.x, 32);
            a0.y += __shfl_down(a0.y, 32);
            a0.z += __shfl_down(a0.z, 32);
            a0.w += __shfl_down(a0.w, 32);
            if (half == 0 && node < n) {
                float d = dis[node];
                float4 b = ld4(&bias[l32 * 4]);
                float4 oV = make_float4(d * a0.x + b.x, d * a0.y + b.y,
                                        d * a0.z + b.z, d * a0.w + b.w);
                uint2 w = make_uint2(pk2(oV.x, oV.y), pk2(oV.z, oV.w));
                reinterpret_cast<uint2*>(outv)[(size_t)node * 32 + l32] = w;
                if (STATS) {
                    st.x += oV.x; sq.x += oV.x * oV.x;
                    st.y += oV.y; sq.y += oV.y * oV.y;
                    st.z += oV.z; sq.z += oV.z * oV.z;
                    st.w += oV.w; sq.w += oV.w * oV.w;
                }
            }
        } else {
            const unsigned* hp = reinterpret_cast<const unsigned*>(hs);  // 32 u32/row
            float2 a0 = make_float2(0.f, 0.f);
            float2 a1 = a0, a2 = a0, a3 = a0;
            if (half == 0 && node < n) {
                unsigned w = hp[(size_t)node * 32 + l32];           // self-loop
                a0 = make_float2(bf_lo(w), bf_hi(w));
            }
            const int lim = e1 - 1;
            for (int e = e0; e < e1; e += 8) {
                int ee0 = e + 0 + half, ee1 = e + 2 + half;
                int ee2 = e + 4 + half, ee3 = e + 6 + half;
                float m0 = (ee0 < e1) ? 1.f : 0.f;
                float m1 = (ee1 < e1) ? 1.f : 0.f;
                float m2 = (ee2 < e1) ? 1.f : 0.f;
                float m3 = (ee3 < e1) ? 1.f : 0.f;
                int i0 = csr[ee0 <= lim ? ee0 : lim];
                int i1 = csr[ee1 <= lim ? ee1 : lim];
                int i2 = csr[ee2 <= lim ? ee2 : lim];
                int i3 = csr[ee3 <= lim ? ee3 : lim];
                unsigned w0 = hp[(size_t)i0 * 32 + l32];
                unsigned w1 = hp[(size_t)i1 * 32 + l32];
                unsigned w2 = hp[(size_t)i2 * 32 + l32];
                unsigned w3 = hp[(size_t)i3 * 32 + l32];
                a0.x = fmaf(m0, bf_lo(w0), a0.x);
                a0.y = fmaf(m0, bf_hi(w0), a0.y);
                a1.x = fmaf(m1, bf_lo(w1), a1.x);
                a1.y = fmaf(m1, bf_hi(w1), a1.y);
                a2.x = fmaf(m2, bf_lo(w2), a2.x);
                a2.y = fmaf(m2, bf_hi(w2), a2.y);
                a3.x = fmaf(m3, bf_lo(w3), a3.x);
                a3.y = fmaf(m3, bf_hi(w3), a3.y);
            }
            a0.x += a1.x + a2.x + a3.x;
            a0.y += a1.y + a2.y + a3.y;
            a0.x += __shfl_down(a0.x, 32);
            a0.y += __shfl_down(a0.y, 32);
            if (half == 0 && node < n) {
                float d = dis[node];
                float2 o = make_float2(d * a0.x + bias[l32 * 2],
                                       d * a0.y + bias[l32 * 2 + 1]);
                reinterpret_cast<float2*>(outv)[(size_t)node * 32 + l32] = o;
            }
        }
    }

    if constexpr (STATS) {
        __shared__ float ls[4][128];
        __shared__ float ls2[4][128];
        if (half == 0) {
            int c = l32 * 4;
            ls[wave][c + 0] = st.x; ls2[wave][c + 0] = sq.x;
            ls[wave][c + 1] = st.y; ls2[wave][c + 1] = sq.y;
            ls[wave][c + 2] = st.z; ls2[wave][c + 2] = sq.z;
            ls[wave][c + 3] = st.w; ls2[wave][c + 3] = sq.w;
        }
        __syncthreads();
        int t = threadIdx.x;
        int slot = (blockIdx.x & (NSLOT - 1)) * 128;
        if (t < 128) {
            atomicAdd(&ssum[slot + t], ls[0][t] + ls[1][t] + ls[2][t] + ls[3][t]);
        } else {
            int c = t - 128;
            atomicAdd(&ssq[slot + c], ls2[0][c] + ls2[1][c] + ls2[2][c] + ls2[3][c]);
        }
    }
}

// Reduce NSLOT partials -> BN affine params a, cc.
__global__ void k_bnparams(const float* __restrict__ ssum, const float* __restrict__ ssq,
                           const float* __restrict__ gamma, const float* __restrict__ beta,
                           float* __restrict__ a, float* __restrict__ cc, int n) {
    int c = threadIdx.x;
    if (c < 128) {
        float s = 0.f, s2 = 0.f;
        for (int k = 0; k < NSLOT; ++k) {
            s += ssum[k * 128 + c];
            s2 += ssq[k * 128 + c];
        }
        float inv_n = 1.0f / (float)n;
        float mean = s * inv_n;
        float var = s2 * inv_n - mean * mean;
        float sc = gamma[c] * rsqrtf(var + 1e-5f);
        a[c] = sc;
        cc[c] = beta[c] - mean * sc;
    }
}

extern "C" void kernel_launch(void* const* d_in, const int* in_sizes, int n_in,
                              void* d_out, int out_size, void* d_ws, size_t ws_size,
                              hipStream_t stream) {
    const float* x      = (const float*)d_in[0];
    const int*   ei     = (const int*)d_in[1];     // [2,E] row-major: src then dst
    const float* W1     = (const float*)d_in[2];
    const float* b1     = (const float*)d_in[3];
    const float* gamma1 = (const float*)d_in[4];
    const float* beta1  = (const float*)d_in[5];
    const float* W2     = (const float*)d_in[6];
    const float* b2     = (const float*)d_in[7];
    const float* gamma2 = (const float*)d_in[8];
    const float* beta2  = (const float*)d_in[9];
    const float* W3     = (const float*)d_in[10];
    const float* b3     = (const float*)d_in[11];
    float* out = (float*)d_out;

    const int n = in_sizes[0] / 128;       // 50000
    const int e = in_sizes[1] / 2;         // 600000
    const int* esrc = ei;
    const int* edst = ei + e;

    // workspace layout (256B aligned chunks)
    char* p = (char*)d_ws;
    auto alloc = [&](size_t bytes) {
        void* r = p;
        p += (bytes + 255) & ~size_t(255);
        return r;
    };
    unsigned short* hbf  = (unsigned short*)alloc(sizeof(unsigned short) * (size_t)n * 128);
    unsigned short* bufB = (unsigned short*)alloc(sizeof(unsigned short) * (size_t)n * 128);
    int*   cnt    = (int*)alloc(sizeof(int) * n);
    int*   offs   = (int*)alloc(sizeof(int) * (n + 1));
    int*   cursor = (int*)alloc(sizeof(int) * n);
    int*   csr    = (int*)alloc(sizeof(int) * e);
    float* dis    = (float*)alloc(sizeof(float) * n);
    float* stats  = (float*)alloc(sizeof(float) * 4 * NSLOT * 128);
    float* bn     = (float*)alloc(sizeof(float) * 512);  // a1,cc1,a2,cc2
    int*   chunkSum = (int*)alloc(sizeof(int) * NCHUNK);
    unsigned short* wf1 = (unsigned short*)alloc(sizeof(unsigned short) * 32 * 64 * 8);
    unsigned short* wf2 = (unsigned short*)alloc(sizeof(unsigned short) * 32 * 64 * 8);
    unsigned short* wf3 = (unsigned short*)alloc(sizeof(unsigned short) * 16 * 64 * 8);
    float* ssum1 = stats,                   *ssq1 = stats + NSLOT * 128;
    float* ssum2 = stats + 2 * NSLOT * 128, *ssq2 = stats + 3 * NSLOT * 128;
    float* a1 = bn, *cc1 = bn + 128, *a2 = bn + 256, *cc2 = bn + 384;

    int gb_n  = (n + 255) / 256;
    int gb_e  = (e + 255) / 256;
    int gb_gemm = (n + 63) / 64;
    int gb_agg = (n + 4 * NPW - 1) / (4 * NPW);

    // setup: init + W prep (merged), count, chunk-scan (2 kernels), scatter
    k_setup<<<gb_n + 20, 256, 0, stream>>>(cnt, stats, n, gb_n, W1, W2, W3, wf1, wf2, wf3);
    k_count<<<gb_e, 256, 0, stream>>>(edst, cnt, e);
    k_chunksum<<<NCHUNK / 256, 256, 0, stream>>>(cnt, chunkSum, n);
    k_chunkwrite<<<NCHUNK / 256, 256, 0, stream>>>(cnt, chunkSum, offs, cursor, dis, n, e);
    k_scatter<<<gb_e, 256, 0, stream>>>(esrc, edst, cursor, csr, e);

    // layer 1
    k_gemm<false, 128, false><<<gb_gemm, 256, 0, stream>>>(x, (const uint4*)wf1, dis, nullptr, nullptr, hbf, n);
    k_agg<128, true><<<gb_agg, 256, 0, stream>>>(hbf, offs, csr, dis, b1, bufB, ssum1, ssq1, n);
    k_bnparams<<<1, 128, 0, stream>>>(ssum1, ssq1, gamma1, beta1, a1, cc1, n);

    // layer 2
    k_gemm<true, 128, true><<<gb_gemm, 256, 0, stream>>>(bufB, (const uint4*)wf2, dis, a1, cc1, hbf, n);
    k_agg<128, true><<<gb_agg, 256, 0, stream>>>(hbf, offs, csr, dis, b2, bufB, ssum2, ssq2, n);
    k_bnparams<<<1, 128, 0, stream>>>(ssum2, ssq2, gamma2, beta2, a2, cc2, n);

    // layer 3 (no BN/ReLU after; fp32 output to d_out)
    k_gemm<true, 64, true><<<gb_gemm, 256, 0, stream>>>(bufB, (const uint4*)wf3, dis, a2, cc2, hbf, n);
    k_agg<64, false><<<gb_agg, 256, 0, stream>>>(hbf, offs, csr, dis, b3, out, nullptr, nullptr, n);
}